// Round 1
// baseline (1268.885 us; speedup 1.0000x reference)
//
#include <hip/hip_runtime.h>
#include <stdint.h>

// Problem constants
#define TT 1024     // tokens
#define HH 2048     // hidden
#define NE 32       // routed experts
#define II 1024     // intermediate
#define NTOPK 6
#define SCALEF 2.5f

typedef __attribute__((ext_vector_type(4))) float f32x4;
typedef __attribute__((ext_vector_type(8))) __bf16 bf16x8;
typedef unsigned short us;

#define GLD16(g, l)                                                                         \
  __builtin_amdgcn_global_load_lds((const __attribute__((address_space(1))) void*)(g),      \
                                   (__attribute__((address_space(3))) void*)(l), 16, 0, 0)

__device__ __forceinline__ unsigned bf16rne(float f) {
    unsigned u = __builtin_bit_cast(unsigned, f);
    return (u + 0x7FFFu + ((u >> 16) & 1u)) >> 16;
}
__device__ __forceinline__ unsigned pack2(float lo, float hi) {
    return bf16rne(lo) | (bf16rne(hi) << 16);
}

// ---------------------------------------------------------------------------
// Kernel 1: convert hidden_states fp32 -> bf16 (row-major [T][H]);
// also initialize "expert 32" (= shared expert) token list with identity.
__global__ void init_convert(const float* __restrict__ x, us* __restrict__ xb,
                             int* __restrict__ cnt, int* __restrict__ tlist,
                             float* __restrict__ twgt) {
    int gid = blockIdx.x * 256 + threadIdx.x;   // 524288 threads, 4 floats each
    const float4* x4 = (const float4*)x;
    float4 v = x4[gid];
    uint2 o;
    o.x = pack2(v.x, v.y);
    o.y = pack2(v.z, v.w);
    ((uint2*)xb)[gid] = o;
    if (gid < TT) {
        tlist[(NE << 10) + gid] = gid;
        twgt[(NE << 10) + gid] = 1.0f;   // shared expert: weight 1.0, no SCALE
    }
    if (gid == 0) cnt[NE] = TT;
}

// ---------------------------------------------------------------------------
// Kernel 2: router. One wave per token.
__global__ void router_kernel(const float* __restrict__ x, const float* __restrict__ gw,
                              const float* __restrict__ bias, int* __restrict__ cnt,
                              int* __restrict__ tlist, float* __restrict__ twgt) {
    int t = blockIdx.x;
    int lane = threadIdx.x;
    int e = lane & 31, h = lane >> 5;
    const float* xr = x + (size_t)t * HH;
    float acc = 0.f;
    #pragma unroll 4
    for (int k = h; k < HH; k += 2)
        acc += xr[k] * gw[k * NE + e];
    acc += __shfl_down(acc, 32);

    __shared__ float sc[NE], sb[NE];
    if (lane < NE) {
        float s = 1.f / (1.f + expf(-acc));
        sc[e] = s;
        sb[e] = s + bias[e];
    }
    __syncthreads();
    if (lane == 0) {
        float gs[8];
        for (int g = 0; g < 8; g++) {
            float m1 = -1e30f, m2 = -1e30f;
            for (int j = 0; j < 4; j++) {
                float v = sb[g * 4 + j];
                if (v > m1) { m2 = m1; m1 = v; }
                else if (v > m2) { m2 = v; }
            }
            gs[g] = m1 + m2;
        }
        unsigned gmask = 0;
        for (int r = 0; r < 4; r++) {
            float best = -1e30f; int bi = 0;
            for (int g = 0; g < 8; g++)
                if (!((gmask >> g) & 1) && gs[g] > best) { best = gs[g]; bi = g; }
            gmask |= 1u << bi;
        }
        int ids[NTOPK]; float wsv[NTOPK]; float sum = 0.f;
        unsigned sel = 0;
        for (int r = 0; r < NTOPK; r++) {
            float best = -1e30f; int bi = 0;
            for (int ee = 0; ee < NE; ee++) {
                if (!((gmask >> (ee >> 2)) & 1)) continue;
                if ((sel >> ee) & 1) continue;
                if (sb[ee] > best) { best = sb[ee]; bi = ee; }
            }
            sel |= 1u << bi;
            ids[r] = bi; wsv[r] = sc[bi]; sum += sc[bi];
        }
        float inv = SCALEF / sum;
        for (int r = 0; r < NTOPK; r++) {
            int ee = ids[r];
            int slot = atomicAdd(&cnt[ee], 1);
            tlist[(ee << 10) + slot] = t;
            twgt[(ee << 10) + slot] = wsv[r] * inv;
        }
    }
}

// ---------------------------------------------------------------------------
// Kernel 3: gate_up GEMM + silu*mul + weight, bf16 MFMA 16x16x32.
// M-tile 256 (avg expert count ~192 -> W streamed ONCE per expert, and each
// packed W byte feeds 2x MFMAs vs the previous 128-tile). N-tile = 32 gate
// + 32 up cols. 4 waves, wave wv owns rows wv*64..+63. Single-barrier
// software-pipelined loop (prefetch after barrier, consumed next iter).
__global__ __launch_bounds__(256, 3)
void gu_gemm(const us* __restrict__ xb,
             const float* __restrict__ wgu, const float* __restrict__ shgu,
             const int* __restrict__ tlist, const float* __restrict__ twgt,
             const int* __restrict__ cnt, us* __restrict__ act) {
    int e = blockIdx.z;
    int count = cnt[e];
    int m0 = blockIdx.y * 256;
    if (m0 >= count) return;
    int n0 = blockIdx.x * 32;                  // gate col base (up col = same)
    const float* wb = (e < NE) ? (wgu + (size_t)e * HH * (2 * II)) : shgu;
    const int* tl = tlist + (e << 10);

    __shared__ __align__(16) us xs[2][256 * 32];     // A tile [m][k] bf16
    __shared__ __align__(16) us ws_[2][2][32 * 40];  // [buf][g/u][n][kpad=40]

    int tid = threadIdx.x;
    int lane = tid & 63, wv = tid >> 6;
    int q = lane >> 4, c = lane & 15;
    int rsub = lane >> 2, j = lane & 3;

    // --- A staging: 4 GLD16 rounds/iter; round r: wave wv -> rows r*64+wv*16..+15
    const us* ag[4];
    int aoff[4];
    #pragma unroll
    for (int r = 0; r < 4; r++) {
        int row = r * 64 + wv * 16 + rsub;
        int m = m0 + row;
        int tok = (m < count) ? tl[m] : 0;
        ag[r] = xb + (size_t)tok * HH + j * 8;
        aoff[r] = (r * 64 + wv * 16) * 32;     // wave-uniform LDS element offset
    }

    // --- W staging mapping: 256 thr cover 32g+32u cols x 32 k fp32 per iter.
    int kp = tid & 15;                 // k-pair index (rows 2kp, 2kp+1)
    int ig = (tid >> 4) & 7;           // 4-col group
    int half = tid >> 7;               // 0 = gate, 1 = up
    const float* wpbase = wb + (size_t)(kp * 2) * (2 * II) + half * II + n0 + ig * 4;
    int di = (ig * 4) * 20 + kp;       // dword idx, row = 20 dwords

    f32x4 accg[4][2] = {};
    f32x4 accu[4][2] = {};

    // prologue: prefetch k0=0 into buf 0 / regs
    #pragma unroll
    for (int r = 0; r < 4; r++) GLD16(ag[r], xs[0] + aoff[r]);
    float4 f0 = *(const float4*)(wpbase);
    float4 f1 = *(const float4*)(wpbase + 2 * II);

    int cur = 0;
    for (int k0 = 0; k0 < HH; k0 += 32) {
        // stage W(k0) regs -> LDS[cur]
        unsigned* wdst = (unsigned*)ws_[cur][half];
        wdst[di]      = pack2(f0.x, f1.x);
        wdst[di + 20] = pack2(f0.y, f1.y);
        wdst[di + 40] = pack2(f0.z, f1.z);
        wdst[di + 60] = pack2(f0.w, f1.w);
        __syncthreads();   // drains prev-iter GLD16 (latency hidden) + LDS writes

        int k1 = k0 + 32;
        if (k1 < HH) {     // prefetch next tile (issued after barrier, used next iter)
            #pragma unroll
            for (int r = 0; r < 4; r++) GLD16(ag[r] + k1, xs[cur ^ 1] + aoff[r]);
            const float* wp = wpbase + (size_t)k1 * (2 * II);
            f0 = *(const float4*)(wp);
            f1 = *(const float4*)(wp + 2 * II);
        }

        const us* xsc = xs[cur];
        const us* wgc = ws_[cur][0];
        const us* wuc = ws_[cur][1];
        bf16x8 a[4];
        #pragma unroll
        for (int tm = 0; tm < 4; tm++)
            a[tm] = *(const bf16x8*)(xsc + (wv * 64 + tm * 16 + c) * 32 + q * 8);
        bf16x8 bg[2], bu[2];
        #pragma unroll
        for (int tn = 0; tn < 2; tn++) {
            bg[tn] = *(const bf16x8*)(wgc + (tn * 16 + c) * 40 + q * 8);
            bu[tn] = *(const bf16x8*)(wuc + (tn * 16 + c) * 40 + q * 8);
        }
        #pragma unroll
        for (int tm = 0; tm < 4; tm++) {
            #pragma unroll
            for (int tn = 0; tn < 2; tn++) {
                accg[tm][tn] = __builtin_amdgcn_mfma_f32_16x16x32_bf16(a[tm], bg[tn], accg[tm][tn], 0, 0, 0);
                accu[tm][tn] = __builtin_amdgcn_mfma_f32_16x16x32_bf16(a[tm], bu[tn], accu[tm][tn], 0, 0, 0);
            }
        }
        cur ^= 1;
    }

    // epilogue: act = silu(g)*u * weight, bf16 store
    const float* twp = twgt + (e << 10);
    #pragma unroll
    for (int tm = 0; tm < 4; tm++) {
        int mlb = wv * 64 + tm * 16 + q * 4;
        #pragma unroll
        for (int r = 0; r < 4; r++) {
            int m = m0 + mlb + r;
            if (m < count) {
                float w = twp[m];
                size_t rowbase = ((size_t)(e << 10) + m) * II + n0;
                #pragma unroll
                for (int tn = 0; tn < 2; tn++) {
                    float g = accg[tm][tn][r];
                    float u = accu[tm][tn][r];
                    float aa = (g / (1.f + __expf(-g))) * u * w;
                    act[rowbase + tn * 16 + c] = (us)bf16rne(aa);
                }
            }
        }
    }
}

// ---------------------------------------------------------------------------
// Kernel 4: down GEMM + scatter-add into out. M-tile 256, N-tile 64,
// same pipelined structure as gu_gemm.
__global__ __launch_bounds__(256, 3)
void down_gemm(const us* __restrict__ act,
               const float* __restrict__ wd, const float* __restrict__ shd,
               const int* __restrict__ tlist, const int* __restrict__ cnt,
               float* __restrict__ out) {
    int e = blockIdx.z;
    int count = cnt[e];
    int m0 = blockIdx.y * 256;
    if (m0 >= count) return;
    int n0 = blockIdx.x * 64;
    const float* wb = (e < NE) ? (wd + (size_t)e * II * HH) : shd;
    const int* tl = tlist + (e << 10);

    __shared__ __align__(16) us as_[2][256 * 32];
    __shared__ __align__(16) us bs[2][64 * 40];

    int tid = threadIdx.x;
    int lane = tid & 63, wv = tid >> 6;
    int q = lane >> 4, c = lane & 15;
    int rsub = lane >> 2, j = lane & 3;

    // A staging: act rows are slot-contiguous (no gather needed). Rows >= count
    // read garbage; their results are discarded in the epilogue.
    const us* ag[4];
    int aoff[4];
    #pragma unroll
    for (int r = 0; r < 4; r++) {
        int row = r * 64 + wv * 16 + rsub;
        ag[r] = act + ((size_t)(e << 10) + m0 + row) * II + j * 8;
        aoff[r] = (r * 64 + wv * 16) * 32;
    }

    int kp = tid & 15;
    int ig = (tid >> 4) & 7;
    int half = tid >> 7;               // col half: 0 -> n0..n0+31, 1 -> +32
    const float* wpbase = wb + (size_t)(kp * 2) * HH + n0 + half * 32 + ig * 4;
    int di = (half * 32 + ig * 4) * 20 + kp;

    f32x4 acc[4][4] = {};

    #pragma unroll
    for (int r = 0; r < 4; r++) GLD16(ag[r], as_[0] + aoff[r]);
    float4 f0 = *(const float4*)(wpbase);
    float4 f1 = *(const float4*)(wpbase + HH);

    int cur = 0;
    for (int k0 = 0; k0 < II; k0 += 32) {
        unsigned* bd = (unsigned*)bs[cur];
        bd[di]      = pack2(f0.x, f1.x);
        bd[di + 20] = pack2(f0.y, f1.y);
        bd[di + 40] = pack2(f0.z, f1.z);
        bd[di + 60] = pack2(f0.w, f1.w);
        __syncthreads();

        int k1 = k0 + 32;
        if (k1 < II) {
            #pragma unroll
            for (int r = 0; r < 4; r++) GLD16(ag[r] + k1, as_[cur ^ 1] + aoff[r]);
            const float* wp = wpbase + (size_t)k1 * HH;
            f0 = *(const float4*)(wp);
            f1 = *(const float4*)(wp + HH);
        }

        const us* asc = as_[cur];
        const us* bsc = bs[cur];
        bf16x8 a[4];
        #pragma unroll
        for (int tm = 0; tm < 4; tm++)
            a[tm] = *(const bf16x8*)(asc + (wv * 64 + tm * 16 + c) * 32 + q * 8);
        #pragma unroll
        for (int tn = 0; tn < 4; tn++) {
            bf16x8 b = *(const bf16x8*)(bsc + (tn * 16 + c) * 40 + q * 8);
            #pragma unroll
            for (int tm = 0; tm < 4; tm++)
                acc[tm][tn] = __builtin_amdgcn_mfma_f32_16x16x32_bf16(a[tm], b, acc[tm][tn], 0, 0, 0);
        }
        cur ^= 1;
    }

    #pragma unroll
    for (int tm = 0; tm < 4; tm++) {
        int mlb = wv * 64 + tm * 16 + q * 4;
        #pragma unroll
        for (int r = 0; r < 4; r++) {
            int m = m0 + mlb + r;
            if (m < count) {
                int tok = tl[m];
                float* op = out + (size_t)tok * HH + n0 + c;
                #pragma unroll
                for (int tn = 0; tn < 4; tn++)
                    unsafeAtomicAdd(op + tn * 16, acc[tm][tn][r]);
            }
        }
    }
}

// ---------------------------------------------------------------------------
extern "C" void kernel_launch(void* const* d_in, const int* in_sizes, int n_in,
                              void* d_out, int out_size, void* d_ws, size_t ws_size,
                              hipStream_t stream) {
    const float* x    = (const float*)d_in[0];
    const float* gw   = (const float*)d_in[1];
    const float* bias = (const float*)d_in[2];
    const float* wgu  = (const float*)d_in[3];
    const float* wd   = (const float*)d_in[4];
    const float* shgu = (const float*)d_in[5];
    const float* shd  = (const float*)d_in[6];
    float* out = (float*)d_out;

    // workspace layout (~74 MB total)
    char* ws = (char*)d_ws;
    int*   cnt   = (int*)ws;                                   // 256 B (33 used)
    int*   tlist = (int*)(ws + 256);                           // 33*1024*4
    float* twgt  = (float*)(ws + 256 + 33 * 1024 * 4);         // 33*1024*4
    us* xb  = (us*)(ws + 256 + 2 * 33 * 1024 * 4);
    us* act = (us*)((char*)xb + (size_t)TT * HH * 2);

    hipMemsetAsync(cnt, 0, 256, stream);
    hipMemsetAsync(out, 0, (size_t)out_size * sizeof(float), stream);
    init_convert<<<dim3((TT * HH / 4) / 256), 256, 0, stream>>>(x, xb, cnt, tlist, twgt);
    router_kernel<<<dim3(TT), 64, 0, stream>>>(x, gw, bias, cnt, tlist, twgt);
    gu_gemm<<<dim3(II / 32, 4, NE + 1), 256, 0, stream>>>(xb, wgu, shgu, tlist, twgt, cnt, act);
    down_gemm<<<dim3(HH / 64, 4, NE + 1), 256, 0, stream>>>(act, wd, shd, tlist, cnt, out);
}